// Round 13
// baseline (2533.085 us; speedup 1.0000x reference)
//
#include <hip/hip_runtime.h>
#include <math.h>

#define P_SEQ 1024
#define E_DIM 512
#define NHEAD 8
#define DK    64
#define BATCH 16
#define M_TOK (BATCH * P_SEQ)   // 16384
#define FF_DIM 2048
#define NLAYER 4

// log2(e)/8 folded into Wq/bq at conversion so attention probs = exp2(Q'K^T)
#define QSCALE 0.1803368801111204f

typedef __attribute__((ext_vector_type(8))) __bf16 bf16x8;
typedef __attribute__((ext_vector_type(4))) float floatx4;
typedef unsigned int u32;
typedef const __attribute__((address_space(1))) u32* gptr_t;
typedef __attribute__((address_space(3))) u32* lptr_t;

__device__ inline float bf2f(unsigned short u) {
  union { unsigned int i; float f; } c; c.i = ((unsigned int)u) << 16; return c.f;
}
__device__ inline unsigned short f2bf(float f) {
  union { float f; unsigned int i; } c; c.f = f;
  unsigned int i = c.i;
  i += 0x7FFFu + ((i >> 16) & 1u);   // RTNE
  return (unsigned short)(i >> 16);
}
__device__ inline bf16x8 ld8(const unsigned short* p) {
  return *reinterpret_cast<const bf16x8*>(p);
}

// Raw v_exp_f32 (1 instruction) — OCML exp2f guard code bloats softmax VALU.
__device__ inline float fast_exp2(float x) {
#if defined(__HIP_DEVICE_COMPILE__) && __has_builtin(__builtin_amdgcn_exp2f)
  return __builtin_amdgcn_exp2f(x);
#else
  return exp2f(x);
#endif
}

// Pack two f32 -> packed bf16 dword (lo in low half).
__device__ inline unsigned int pkbf16(float lo, float hi) {
#if defined(__HIP_DEVICE_COMPILE__) && __has_builtin(__builtin_amdgcn_cvt_pk_bf16_f32)
  typedef __attribute__((ext_vector_type(2))) __bf16 bf16x2;
  bf16x2 v = __builtin_amdgcn_cvt_pk_bf16_f32(lo, hi);
  return __builtin_bit_cast(unsigned int, v);
#else
  return (unsigned int)f2bf(lo) | ((unsigned int)f2bf(hi) << 16);
#endif
}

// Raw barrier WITHOUT the vmcnt(0) drain __syncthreads() forces: waits only
// LDS ops. Lets buffer_loads stay in flight across the barrier (the AITER
// pattern the HIP compiler otherwise defeats).
__device__ inline void lds_barrier() {
  __asm__ volatile("s_waitcnt lgkmcnt(0)\n\ts_barrier" ::: "memory");
}

// ---------------------------------------------------------------------------
// Dtype detector (bf16 vs fp32 harness storage).
// ---------------------------------------------------------------------------
__global__ void detect_dtype(const unsigned short* __restrict__ data, int* __restrict__ flag) {
  if (threadIdx.x == 0) {
    int sane = 0;
    for (int i = 0; i < 256; i++) {
      int e = (data[i] >> 7) & 0xFF;
      if (e >= 107 && e <= 133) sane++;
    }
    *flag = (sane >= 240) ? 0 : 1;
  }
}

// ---------------------------------------------------------------------------
// Fused conversion + QKV packing (all bounds literal -> no scratch).
// ---------------------------------------------------------------------------
#define C_DATA 0
#define C_WO   65536
#define C_BO   1114112
#define C_LN1G 1116160
#define C_LN1B 1118208
#define C_LN2G 1120256
#define C_LN2B 1122304
#define C_W1   1124352
#define C_B1   5318656
#define C_W2   5326848
#define C_B2   9521152
#define C_CW   9523200
#define C_CB   9523208
#define C_LW   9523216
#define C_LB   9523728
#define C_WC   9524240
#define C_BC   9524752

struct ConvArgs {
  const void* src[23];
  unsigned short* canon;
  unsigned short* wqkv;
  unsigned short* bqkv;
  const int* flag;
};

__global__ __launch_bounds__(256) void convert_pack(ConvArgs a)
{
  const int i = blockIdx.x * 256 + threadIdx.x;
  const bool f32 = (*a.flag != 0);
  #define LOADF(IDX, J) (f32 ? ((const float*)a.src[IDX])[J] \
                             : bf2f(((const unsigned short*)a.src[IDX])[J]))
  int base = 0;
  if (i < base + 1048576) {
    const int j = i - base, l = j >> 18, rem = j & 262143;
    a.wqkv[l * 786432 + rem] = f2bf(LOADF(5, j) * QSCALE);
    return;
  } base += 1048576;
  if (i < base + 1048576) {
    const int j = i - base, l = j >> 18, rem = j & 262143;
    a.wqkv[l * 786432 + 262144 + rem] = f2bf(LOADF(7, j));
    return;
  } base += 1048576;
  if (i < base + 1048576) {
    const int j = i - base, l = j >> 18, rem = j & 262143;
    a.wqkv[l * 786432 + 524288 + rem] = f2bf(LOADF(9, j));
    return;
  } base += 1048576;
  if (i < base + 4194304) {
    const int j = i - base;
    a.canon[C_W1 + j] = f2bf(LOADF(17, j));
    return;
  } base += 4194304;
  if (i < base + 4194304) {
    const int j = i - base;
    a.canon[C_W2 + j] = f2bf(LOADF(19, j));
    return;
  } base += 4194304;
  if (i < base + 1048576) {
    const int j = i - base;
    a.canon[C_WO + j] = f2bf(LOADF(11, j));
    return;
  } base += 1048576;
  if (i < base + 65536) {
    const int j = i - base;
    a.canon[C_DATA + j] = f2bf(LOADF(0, j));
    return;
  } base += 65536;
  if (i < base + 2048) {
    const int j = i - base, l = j >> 9, r = j & 511;
    a.bqkv[l * 1536 + r] = f2bf(LOADF(6, j) * QSCALE);
    return;
  } base += 2048;
  if (i < base + 2048) {
    const int j = i - base, l = j >> 9, r = j & 511;
    a.bqkv[l * 1536 + 512 + r] = f2bf(LOADF(8, j));
    return;
  } base += 2048;
  if (i < base + 2048) {
    const int j = i - base, l = j >> 9, r = j & 511;
    a.bqkv[l * 1536 + 1024 + r] = f2bf(LOADF(10, j));
    return;
  } base += 2048;
  if (i < base + 2048) { a.canon[C_BO   + i - base] = f2bf(LOADF(12, i - base)); return; } base += 2048;
  if (i < base + 2048) { a.canon[C_LN1G + i - base] = f2bf(LOADF(13, i - base)); return; } base += 2048;
  if (i < base + 2048) { a.canon[C_LN1B + i - base] = f2bf(LOADF(14, i - base)); return; } base += 2048;
  if (i < base + 2048) { a.canon[C_LN2G + i - base] = f2bf(LOADF(15, i - base)); return; } base += 2048;
  if (i < base + 2048) { a.canon[C_LN2B + i - base] = f2bf(LOADF(16, i - base)); return; } base += 2048;
  if (i < base + 8192) { a.canon[C_B1   + i - base] = f2bf(LOADF(18, i - base)); return; } base += 8192;
  if (i < base + 2048) { a.canon[C_B2   + i - base] = f2bf(LOADF(20, i - base)); return; } base += 2048;
  if (i < base + 4)   { a.canon[C_CW + i - base] = f2bf(LOADF(1, i - base)); return; } base += 4;
  if (i < base + 1)   { a.canon[C_CB + i - base] = f2bf(LOADF(2, i - base)); return; } base += 1;
  if (i < base + 512) { a.canon[C_LW + i - base] = f2bf(LOADF(3, i - base)); return; } base += 512;
  if (i < base + 512) { a.canon[C_LB + i - base] = f2bf(LOADF(4, i - base)); return; } base += 512;
  if (i < base + 512) { a.canon[C_WC + i - base] = f2bf(LOADF(21, i - base)); return; } base += 512;
  if (i < base + 1)   { a.canon[C_BC + i - base] = f2bf(LOADF(22, i - base)); return; }
  #undef LOADF
}
#define CONV_TOTAL (3*1048576 + 2*4194304 + 1048576 + 65536 + 3*2048 + 7*2048 + 8192 - 2048 + 4 + 1 + 512 + 512 + 512 + 1)

// ---------------------------------------------------------------------------
// Tiled GEMM v2: reg-staged software pipeline. Single 32 KB LDS buffer;
// per tile: buffer_load next -> VGPRs, compute current from LDS, raw
// lds_barrier (no vmcnt drain), ds_write regs -> LDS, load tile+2, barrier.
// The vmcnt wait for a tile's loads lands at its ds_write — AFTER a full
// compute phase. Same LDS layout as before: position p of row r holds global
// 8-elem block p^(r&7) (A) / p^((r>>2)&7) (B), so reads/compute/epilogue are
// unchanged from the passing round-12 kernel. ds_writes are bank-balanced
// (8 lanes per 16B position = b128 floor).
// MODE 0: bias  1: bias+relu  4: fused QKV epilogue (Q/K [b,h,p,d], V^T)
// ---------------------------------------------------------------------------
#define BM 128
#define BN 128
#define BK 64

template <int MODE>
__global__ __launch_bounds__(256, 3) void gemm_tile(
    const unsigned short* __restrict__ X, const unsigned short* __restrict__ W,
    const unsigned short* __restrict__ bias, unsigned short* __restrict__ Y,
    int M, int N, int Kd)
{
  __shared__ __align__(16) unsigned short As[BM * BK];
  __shared__ __align__(16) unsigned short Bs[BN * BK];

  const int tid  = threadIdx.x;
  const int lane = tid & 63;
  const int wave = tid >> 6;
  const int wm = wave & 1, wn = wave >> 1;
  const int col = lane & 15, quad = lane >> 4;

  const int m0 = blockIdx.y * BM;
  const int n0 = blockIdx.x * BN;

  const int srow = tid >> 3;   // 0..31
  const int scb  = tid & 7;

  floatx4 acc[4][4] = {};

  uint4 ar[4], br[4];
  const unsigned short* xb = X + (size_t)(m0 + srow) * Kd + scb * 8;
  const unsigned short* wb = W + (size_t)(n0 + srow) * Kd + scb * 8;

  auto load_regs = [&](int kt) {
    #pragma unroll
    for (int i = 0; i < 4; i++) {
      ar[i] = *reinterpret_cast<const uint4*>(xb + (size_t)(i * 32) * Kd + kt);
      br[i] = *reinterpret_cast<const uint4*>(wb + (size_t)(i * 32) * Kd + kt);
    }
  };
  auto write_lds = [&]() {
    #pragma unroll
    for (int i = 0; i < 4; i++) {
      const int r = i * 32 + srow;
      *reinterpret_cast<uint4*>(&As[r * BK + ((scb ^ (r & 7)) << 3)]) = ar[i];
      *reinterpret_cast<uint4*>(&Bs[r * BK + ((scb ^ ((r >> 2) & 7)) << 3)]) = br[i];
    }
  };

  const int NT = Kd / BK;
  load_regs(0);
  write_lds();                    // compiler inserts exact vmcnt wait
  if (NT > 1) load_regs(BK);      // tile 1 in flight across the barrier
  lds_barrier();

  for (int c = 0; c < NT; c++) {
    #pragma unroll
    for (int kk = 0; kk < 2; kk++) {
      bf16x8 af[4], bfr[4];
      #pragma unroll
      for (int t = 0; t < 4; t++) {
        const int mr = wm * 64 + t * 16 + col;
        const int ka = (kk * 4 + quad) ^ (mr & 7);
        af[t] = ld8(&As[mr * BK + ka * 8]);
        const int nr = wn * 64 + col * 4 + t;
        const int kb = (kk * 4 + quad) ^ (col & 7);
        bfr[t] = ld8(&Bs[nr * BK + kb * 8]);
      }
      #pragma unroll
      for (int mt = 0; mt < 4; mt++)
        #pragma unroll
        for (int nt = 0; nt < 4; nt++)
          acc[mt][nt] = __builtin_amdgcn_mfma_f32_16x16x32_bf16(af[mt], bfr[nt], acc[mt][nt], 0, 0, 0);
    }
    if (c + 1 < NT) {
      lds_barrier();              // all waves done reading tile c
      write_lds();                // tile c+1 (vmcnt wait here, post-compute)
      if (c + 2 < NT) load_regs((c + 2) * BK);
      lds_barrier();              // tile c+1 visible
    }
  }

  const int col4 = n0 + wn * 64 + col * 4;
  float bb[4];
  {
    const uint2 bu = *reinterpret_cast<const uint2*>(&bias[col4]);
    bb[0] = bf2f((unsigned short)(bu.x & 0xffffu));
    bb[1] = bf2f((unsigned short)(bu.x >> 16));
    bb[2] = bf2f((unsigned short)(bu.y & 0xffffu));
    bb[3] = bf2f((unsigned short)(bu.y >> 16));
  }

  if (MODE == 4 && (col4 >> 9) == 2) {
    const int cc0 = col4 & 511;
    const int h = cc0 >> 6;
    #pragma unroll
    for (int nt = 0; nt < 4; nt++) {
      const int d = (cc0 + nt) & 63;
      #pragma unroll
      for (int mt = 0; mt < 4; mt++) {
        const int p0 = m0 + wm * 64 + mt * 16 + quad * 4;
        const int b = p0 >> 10, p = p0 & 1023;
        float v0 = acc[mt][nt][0] + bb[nt], v1 = acc[mt][nt][1] + bb[nt];
        float v2 = acc[mt][nt][2] + bb[nt], v3 = acc[mt][nt][3] + bb[nt];
        const size_t idx = 16777216 + (((size_t)(b * NHEAD + h) * DK) + d) * P_SEQ + p;
        *reinterpret_cast<uint2*>(&Y[idx]) = make_uint2(pkbf16(v0, v1), pkbf16(v2, v3));
      }
    }
  } else {
    const int third = col4 >> 9;
    const int cc0 = col4 & 511;
    const int h = cc0 >> 6, d0 = cc0 & 63;
    #pragma unroll
    for (int mt = 0; mt < 4; mt++) {
      #pragma unroll
      for (int r = 0; r < 4; r++) {
        const int rr = m0 + wm * 64 + mt * 16 + quad * 4 + r;
        float v0 = acc[mt][0][r] + bb[0], v1 = acc[mt][1][r] + bb[1];
        float v2 = acc[mt][2][r] + bb[2], v3 = acc[mt][3][r] + bb[3];
        if (MODE == 1) {
          v0 = fmaxf(v0, 0.f); v1 = fmaxf(v1, 0.f);
          v2 = fmaxf(v2, 0.f); v3 = fmaxf(v3, 0.f);
        }
        size_t idx;
        if (MODE == 4) {
          const int b = rr >> 10, p = rr & 1023;
          idx = (size_t)third * 8388608 + (((size_t)(b * NHEAD + h) * P_SEQ) + p) * DK + d0;
        } else {
          idx = (size_t)rr * N + col4;
        }
        *reinterpret_cast<uint2*>(&Y[idx]) = make_uint2(pkbf16(v0, v1), pkbf16(v2, v3));
      }
    }
  }
}

// ---------------------------------------------------------------------------
// Flash attention (round-12 state, known 59.6 us): 40 KB LDS, 4 blocks/CU,
// per-wave Ps reused across q-tiles, conflict-free V path, exp2 fast path,
// coalesced O store through Ps.
// ---------------------------------------------------------------------------
typedef __attribute__((ext_vector_type(8))) unsigned short ushortx8;

__global__ __launch_bounds__(256, 4) void attn_flash8(
    const unsigned short* __restrict__ Q, const unsigned short* __restrict__ K,
    const unsigned short* __restrict__ Vt, unsigned short* __restrict__ O)
{
  __shared__ __align__(16) unsigned short Ks[2][64 * 64];
  __shared__ __align__(16) unsigned short Vs[2][64 * 64];
  __shared__ __align__(16) unsigned short Ps[4][16 * 64];

  const int tid  = threadIdx.x;
  const int lane = tid & 63;
  const int wave = tid >> 6;
  const int col  = lane & 15, quad = lane >> 4;
  const int bh = blockIdx.x & 127;
  const int qb0 = (blockIdx.x >> 7) * 128 + wave * 32;

  const unsigned short* Qh = Q  + (size_t)bh * P_SEQ * DK;
  const unsigned short* Kh = K  + (size_t)bh * P_SEQ * DK;
  const unsigned short* Vh = Vt + (size_t)bh * DK * P_SEQ;

  bf16x8 aq[2][2];
  #pragma unroll
  for (int t = 0; t < 2; t++) {
    aq[t][0] = ld8(Qh + (size_t)(qb0 + t * 16 + col) * DK + quad * 8);
    aq[t][1] = ld8(Qh + (size_t)(qb0 + t * 16 + col) * DK + 32 + quad * 8);
  }

  const ushortx8 one_raw = {0x3F80, 0x3F80, 0x3F80, 0x3F80, 0x3F80, 0x3F80, 0x3F80, 0x3F80};
  const bf16x8 ones = __builtin_bit_cast(bf16x8, one_raw);

  floatx4 o[2][4] = {};
  floatx4 lacc[2] = {};

  const int srow = tid >> 3;
  const int scb  = tid & 7;

  auto stage = [&](int kk, int buf) {
    #pragma unroll
    for (int i = 0; i < 2; i++) {
      const int r  = i * 32 + srow;
      const int cb = scb ^ (r & 7);
      __builtin_amdgcn_global_load_lds(
          (gptr_t)(const void*)(Kh + (size_t)(kk + r) * DK + cb * 8),
          (lptr_t)(void*)&Ks[buf][r * 64 + scb * 8], 16, 0, 0);
      __builtin_amdgcn_global_load_lds(
          (gptr_t)(const void*)(Vh + (size_t)r * P_SEQ + kk + cb * 8),
          (lptr_t)(void*)&Vs[buf][r * 64 + scb * 8], 16, 0, 0);
    }
  };

  stage(0, 0);

  for (int c = 0; c < 16; c++) {
    const int buf = c & 1;
    __syncthreads();
    if (c < 15) stage((c + 1) * 64, buf ^ 1);

    bf16x8 kb0[4], kb1[4];
    #pragma unroll
    for (int nt = 0; nt < 4; nt++) {
      const int kr = nt * 16 + col;
      kb0[nt] = ld8(&Ks[buf][kr * 64 + ((quad       ^ (kr & 7)) << 3)]);
      kb1[nt] = ld8(&Ks[buf][kr * 64 + (((4 + quad) ^ (kr & 7)) << 3)]);
    }

    floatx4 s[2][4] = {};
    #pragma unroll
    for (int t = 0; t < 2; t++)
      #pragma unroll
      for (int nt = 0; nt < 4; nt++) {
        s[t][nt] = __builtin_amdgcn_mfma_f32_16x16x32_bf16(aq[t][0], kb0[nt], s[t][nt], 0, 0, 0);
        s[t][nt] = __builtin_amdgcn_mfma_f32_16x16x32_bf16(aq[t][1], kb1[nt], s[t][nt], 0, 0, 0);
      }

    bf16x8 pa[2][2];
    #pragma unroll
    for (int t = 0; t < 2; t++) {
      #pragma unroll
      for (int r = 0; r < 4; r++) {
        const int row = quad * 4 + r;
        unsigned short* pr = &Ps[wave][row * 64];
        #pragma unroll
        for (int nt = 0; nt < 4; nt++) {
          const float p = fast_exp2(fminf(s[t][nt][r], 126.f));
          union { float f; unsigned int u; } pu; pu.f = p;
          const int key = nt * 16 + col;
          pr[(((key >> 3) ^ (row & 7)) << 3) | (key & 7)] = (unsigned short)(pu.u >> 16);
        }
      }
      __asm__ volatile("s_waitcnt lgkmcnt(0)" ::: "memory");
      pa[t][0] = ld8(&Ps[wave][col * 64 + ((quad       ^ (col & 7)) << 3)]);
      pa[t][1] = ld8(&Ps[wave][col * 64 + (((4 + quad) ^ (col & 7)) << 3)]);
      lacc[t] = __builtin_amdgcn_mfma_f32_16x16x32_bf16(pa[t][0], ones, lacc[t], 0, 0, 0);
      lacc[t] = __builtin_amdgcn_mfma_f32_16x16x32_bf16(pa[t][1], ones, lacc[t], 0, 0, 0);
    }

    #pragma unroll
    for (int dt = 0; dt < 4; dt++) {
      const int dr = dt * 16 + col;
      const bf16x8 v0 = ld8(&Vs[buf][dr * 64 + ((quad       ^ (dr & 7)) << 3)]);
      const bf16x8 v1 = ld8(&Vs[buf][dr * 64 + (((4 + quad) ^ (dr & 7)) << 3)]);
      #pragma unroll
      for (int t = 0; t < 2; t++) {
        o[t][dt] = __builtin_amdgcn_mfma_f32_16x16x32_bf16(pa[t][0], v0, o[t][dt], 0, 0, 0);
        o[t][dt] = __builtin_amdgcn_mfma_f32_16x16x32_bf16(pa[t][1], v1, o[t][dt], 0, 0, 0);
      }
    }
  }

  const int b = bh >> 3, h = bh & 7;
  #pragma unroll
  for (int t = 0; t < 2; t++) {
    #pragma unroll
    for (int r = 0; r < 4; r++) {
      const float inv = 1.f / lacc[t][r];
      unsigned short* pr = &Ps[wave][(quad * 4 + r) * 64];
      #pragma unroll
      for (int dt = 0; dt < 4; dt++)
        pr[dt * 16 + col] = f2bf(o[t][dt][r] * inv);
    }
    __asm__ volatile("s_waitcnt lgkmcnt(0)" ::: "memory");
    #pragma unroll
    for (int r = 0; r < 4; r++) {
      const int p = qb0 + t * 16 + quad * 4 + r;
      const uint2 v = *reinterpret_cast<const uint2*>(&Ps[wave][(quad * 4 + r) * 64 + col * 4]);
      *reinterpret_cast<uint2*>(&O[((size_t)(b * P_SEQ + p)) * E_DIM + h * DK + col * 4]) = v;
    }
  }
}

// ---------------------------------------------------------------------------
// Residual add + LayerNorm, 4 rows/block, in place into X.
// ---------------------------------------------------------------------------
__global__ __launch_bounds__(256) void add_ln4(
    unsigned short* __restrict__ X, const unsigned short* __restrict__ R,
    const unsigned short* __restrict__ g, const unsigned short* __restrict__ bta)
{
  const int row  = blockIdx.x * 4 + (threadIdx.x >> 6);
  const int lane = threadIdx.x & 63;
  const size_t base = (size_t)row * E_DIM + lane * 8;

  uint4 xu = *reinterpret_cast<const uint4*>(X + base);
  uint4 ru = *reinterpret_cast<const uint4*>(R + base);
  unsigned int xs[4] = {xu.x, xu.y, xu.z, xu.w};
  unsigned int rs[4] = {ru.x, ru.y, ru.z, ru.w};

  float v[8];
  float s = 0.f;
  #pragma unroll
  for (int i = 0; i < 4; i++) {
    v[2*i]   = bf2f((unsigned short)(xs[i] & 0xffffu)) + bf2f((unsigned short)(rs[i] & 0xffffu));
    v[2*i+1] = bf2f((unsigned short)(xs[i] >> 16))     + bf2f((unsigned short)(rs[i] >> 16));
    s += v[2*i] + v[2*i+1];
  }
  #pragma unroll
  for (int off = 1; off < 64; off <<= 1) s += __shfl_xor(s, off, 64);
  const float mu = s * (1.f / 512.f);

  float var = 0.f;
  #pragma unroll
  for (int i = 0; i < 8; i++) { float d = v[i] - mu; var += d * d; }
  #pragma unroll
  for (int off = 1; off < 64; off <<= 1) var += __shfl_xor(var, off, 64);
  const float rstd = rsqrtf(var * (1.f / 512.f) + 1e-5f);

  unsigned int ow[4];
  #pragma unroll
  for (int i = 0; i < 4; i++) {
    int e0 = lane * 8 + 2 * i;
    float y0 = (v[2*i]   - mu) * rstd * bf2f(g[e0])     + bf2f(bta[e0]);
    float y1 = (v[2*i+1] - mu) * rstd * bf2f(g[e0 + 1]) + bf2f(bta[e0 + 1]);
    ow[i] = pkbf16(y0, y1);
  }
  *reinterpret_cast<uint4*>(X + base) = make_uint4(ow[0], ow[1], ow[2], ow[3]);
}

// ---------------------------------------------------------------------------
// Embedding: conv(2x2) -> Linear(1->E) -> + positional encoding.
// ---------------------------------------------------------------------------
__global__ __launch_bounds__(64) void embed_kernel(
    const unsigned short* __restrict__ canon, unsigned short* __restrict__ X)
{
  const unsigned short* data   = canon + C_DATA;
  const unsigned short* conv_w = canon + C_CW;
  const unsigned short* conv_b = canon + C_CB;
  const unsigned short* lin_w  = canon + C_LW;
  const unsigned short* lin_b  = canon + C_LB;
  const int bp = blockIdx.x;
  const int b = bp >> 10, p = bp & 1023;
  const int ph = p >> 5, pw = p & 31;
  const unsigned short* dr = data + ((size_t)b * 64 + ph * 2) * 64 + pw * 2;
  const float c = bf2f(dr[0])  * bf2f(conv_w[0]) + bf2f(dr[1])  * bf2f(conv_w[1])
                + bf2f(dr[64]) * bf2f(conv_w[2]) + bf2f(dr[65]) * bf2f(conv_w[3])
                + bf2f(conv_b[0]);
  const int lane = threadIdx.x;
  unsigned int ow[4];
  #pragma unroll
  for (int i = 0; i < 4; i++) {
    const int e0 = lane * 8 + 2 * i;
    const float fr = __expf(-(float)e0 * (9.210340371976184f / 512.f));
    const float ang = (float)p * fr;
    const float v0 = c * bf2f(lin_w[e0])     + bf2f(lin_b[e0])     + sinf(ang);
    const float v1 = c * bf2f(lin_w[e0 + 1]) + bf2f(lin_b[e0 + 1]) + cosf(ang);
    ow[i] = pkbf16(v0, v1);
  }
  *reinterpret_cast<uint4*>(X + (size_t)bp * E_DIM + lane * 8) =
      make_uint4(ow[0], ow[1], ow[2], ow[3]);
}

// ---------------------------------------------------------------------------
// Two-stage mean-pool + classifier.
// ---------------------------------------------------------------------------
__global__ __launch_bounds__(256) void classify_partial(
    const unsigned short* __restrict__ X, const unsigned short* __restrict__ Wc,
    float* __restrict__ partial)
{
  const int b = blockIdx.x, sl = blockIdx.y;
  const int tid = threadIdx.x;
  const unsigned short* xb = X + (size_t)b * P_SEQ * E_DIM + (size_t)sl * 128 * E_DIM;
  float s0 = 0.f, s1 = 0.f;
  for (int p = 0; p < 128; p++) {
    s0 += bf2f(xb[(size_t)p * E_DIM + tid]);
    s1 += bf2f(xb[(size_t)p * E_DIM + tid + 256]);
  }
  float acc = s0 * bf2f(Wc[tid]) + s1 * bf2f(Wc[tid + 256]);
  #pragma unroll
  for (int off = 1; off < 64; off <<= 1) acc += __shfl_xor(acc, off, 64);
  __shared__ float red[4];
  if ((tid & 63) == 0) red[tid >> 6] = acc;
  __syncthreads();
  if (tid == 0) partial[b * 8 + sl] = red[0] + red[1] + red[2] + red[3];
}

__global__ __launch_bounds__(64) void classify_final(
    const float* __restrict__ partial, const unsigned short* __restrict__ bc,
    void* __restrict__ out, const int* __restrict__ flag)
{
  const int b = threadIdx.x;
  if (b >= BATCH) return;
  float s = 0.f;
  #pragma unroll
  for (int i = 0; i < 8; i++) s += partial[b * 8 + i];
  float r = s * (1.f / 1024.f) + bf2f(bc[0]);
  if (*flag) ((float*)out)[b] = r;
  else       ((unsigned short*)out)[b] = f2bf(r);
}

// ---------------------------------------------------------------------------
extern "C" void kernel_launch(void* const* d_in, const int* in_sizes, int n_in,
                              void* d_out, int out_size, void* d_ws, size_t ws_size,
                              hipStream_t stream)
{
  char* ws = (char*)d_ws;
  const size_t MB = (size_t)1 << 20;

  unsigned short* canon = (unsigned short*)ws;                 // ~19 MB
  int* flag = (int*)(ws + 176 * MB);
  float* partial = (float*)(ws + 176 * MB + 256);
  unsigned short* wqkv = (unsigned short*)(ws + 177 * MB);     // [4][1536][512]
  unsigned short* bqkv = (unsigned short*)(ws + 184 * MB);     // [4][1536]

  unsigned short* x    = (unsigned short*)(ws + 32 * MB);
  unsigned short* qb   = (unsigned short*)(ws + 48 * MB);      // q|k|vt packed 48 MB
  unsigned short* attn = (unsigned short*)(ws + 96 * MB);
  unsigned short* hbuf = (unsigned short*)(ws + 112 * MB);
  unsigned short* obuf = (unsigned short*)(ws + 144 * MB);
  unsigned short* fbuf = attn;

  const unsigned short* kb  = qb + 8388608;
  const unsigned short* vtb = qb + 16777216;

  detect_dtype<<<1, 64, 0, stream>>>((const unsigned short*)d_in[0], flag);

  ConvArgs ca;
  for (int i = 0; i < 23; i++) ca.src[i] = d_in[i];
  ca.canon = canon; ca.wqkv = wqkv; ca.bqkv = bqkv; ca.flag = flag;
  convert_pack<<<(CONV_TOTAL + 255) / 256, 256, 0, stream>>>(ca);

  embed_kernel<<<dim3(M_TOK), dim3(64), 0, stream>>>(canon, x);

  for (int l = 0; l < NLAYER; l++) {
    const unsigned short* Wqkv_l = wqkv + (size_t)l * 1536 * 512;
    const unsigned short* bqkv_l = bqkv + l * 1536;
    const unsigned short* Wo_l = canon + C_WO + (size_t)l * E_DIM * E_DIM;
    const unsigned short* W1_l = canon + C_W1 + (size_t)l * FF_DIM * E_DIM;
    const unsigned short* W2_l = canon + C_W2 + (size_t)l * E_DIM * FF_DIM;

    gemm_tile<4><<<dim3(1536 / BN, M_TOK / BM), dim3(256), 0, stream>>>(
        x, Wqkv_l, bqkv_l, qb, M_TOK, 1536, E_DIM);

    attn_flash8<<<dim3((P_SEQ / 128) * BATCH * NHEAD), dim3(256), 0, stream>>>(
        qb, kb, vtb, attn);

    gemm_tile<0><<<dim3(E_DIM / BN, M_TOK / BM), dim3(256), 0, stream>>>(
        attn, Wo_l, canon + C_BO + l * E_DIM, obuf, M_TOK, E_DIM, E_DIM);
    add_ln4<<<dim3(M_TOK / 4), dim3(256), 0, stream>>>(
        x, obuf, canon + C_LN1G + l * E_DIM, canon + C_LN1B + l * E_DIM);

    gemm_tile<1><<<dim3(FF_DIM / BN, M_TOK / BM), dim3(256), 0, stream>>>(
        x, W1_l, canon + C_B1 + l * FF_DIM, hbuf, M_TOK, FF_DIM, E_DIM);
    gemm_tile<0><<<dim3(E_DIM / BN, M_TOK / BM), dim3(256), 0, stream>>>(
        hbuf, W2_l, canon + C_B2 + l * E_DIM, fbuf, M_TOK, E_DIM, FF_DIM);
    add_ln4<<<dim3(M_TOK / 4), dim3(256), 0, stream>>>(
        x, fbuf, canon + C_LN2G + l * E_DIM, canon + C_LN2B + l * E_DIM);
  }

  classify_partial<<<dim3(BATCH, 8), dim3(256), 0, stream>>>(x, canon + C_WC, partial);
  classify_final<<<dim3(1), dim3(64), 0, stream>>>(partial, canon + C_BC, d_out, flag);
}

// Round 14
// 1037.013 us; speedup vs baseline: 2.4427x; 2.4427x over previous
//
#include <hip/hip_runtime.h>
#include <math.h>

#define P_SEQ 1024
#define E_DIM 512
#define NHEAD 8
#define DK    64
#define BATCH 16
#define M_TOK (BATCH * P_SEQ)   // 16384
#define FF_DIM 2048
#define NLAYER 4

// log2(e)/8 folded into Wq/bq at conversion so attention probs = exp2(Q'K^T)
#define QSCALE 0.1803368801111204f

typedef __attribute__((ext_vector_type(8))) __bf16 bf16x8;
typedef __attribute__((ext_vector_type(4))) float floatx4;
typedef unsigned int u32;
typedef const __attribute__((address_space(1))) u32* gptr_t;
typedef __attribute__((address_space(3))) u32* lptr_t;

__device__ inline float bf2f(unsigned short u) {
  union { unsigned int i; float f; } c; c.i = ((unsigned int)u) << 16; return c.f;
}
__device__ inline unsigned short f2bf(float f) {
  union { float f; unsigned int i; } c; c.f = f;
  unsigned int i = c.i;
  i += 0x7FFFu + ((i >> 16) & 1u);   // RTNE
  return (unsigned short)(i >> 16);
}
__device__ inline bf16x8 ld8(const unsigned short* p) {
  return *reinterpret_cast<const bf16x8*>(p);
}

// Raw v_exp_f32 (1 instruction) — OCML exp2f guard code bloats softmax VALU.
__device__ inline float fast_exp2(float x) {
#if defined(__HIP_DEVICE_COMPILE__) && __has_builtin(__builtin_amdgcn_exp2f)
  return __builtin_amdgcn_exp2f(x);
#else
  return exp2f(x);
#endif
}

// Pack two f32 -> packed bf16 dword (lo in low half).
__device__ inline unsigned int pkbf16(float lo, float hi) {
#if defined(__HIP_DEVICE_COMPILE__) && __has_builtin(__builtin_amdgcn_cvt_pk_bf16_f32)
  typedef __attribute__((ext_vector_type(2))) __bf16 bf16x2;
  bf16x2 v = __builtin_amdgcn_cvt_pk_bf16_f32(lo, hi);
  return __builtin_bit_cast(unsigned int, v);
#else
  return (unsigned int)f2bf(lo) | ((unsigned int)f2bf(hi) << 16);
#endif
}

// ---------------------------------------------------------------------------
// Dtype detector (bf16 vs fp32 harness storage).
// ---------------------------------------------------------------------------
__global__ void detect_dtype(const unsigned short* __restrict__ data, int* __restrict__ flag) {
  if (threadIdx.x == 0) {
    int sane = 0;
    for (int i = 0; i < 256; i++) {
      int e = (data[i] >> 7) & 0xFF;
      if (e >= 107 && e <= 133) sane++;
    }
    *flag = (sane >= 240) ? 0 : 1;
  }
}

// ---------------------------------------------------------------------------
// Fused conversion + QKV packing (all bounds literal -> no scratch).
// ---------------------------------------------------------------------------
#define C_DATA 0
#define C_WO   65536
#define C_BO   1114112
#define C_LN1G 1116160
#define C_LN1B 1118208
#define C_LN2G 1120256
#define C_LN2B 1122304
#define C_W1   1124352
#define C_B1   5318656
#define C_W2   5326848
#define C_B2   9521152
#define C_CW   9523200
#define C_CB   9523208
#define C_LW   9523216
#define C_LB   9523728
#define C_WC   9524240
#define C_BC   9524752

struct ConvArgs {
  const void* src[23];
  unsigned short* canon;
  unsigned short* wqkv;
  unsigned short* bqkv;
  const int* flag;
};

__global__ __launch_bounds__(256) void convert_pack(ConvArgs a)
{
  const int i = blockIdx.x * 256 + threadIdx.x;
  const bool f32 = (*a.flag != 0);
  #define LOADF(IDX, J) (f32 ? ((const float*)a.src[IDX])[J] \
                             : bf2f(((const unsigned short*)a.src[IDX])[J]))
  int base = 0;
  if (i < base + 1048576) {
    const int j = i - base, l = j >> 18, rem = j & 262143;
    a.wqkv[l * 786432 + rem] = f2bf(LOADF(5, j) * QSCALE);
    return;
  } base += 1048576;
  if (i < base + 1048576) {
    const int j = i - base, l = j >> 18, rem = j & 262143;
    a.wqkv[l * 786432 + 262144 + rem] = f2bf(LOADF(7, j));
    return;
  } base += 1048576;
  if (i < base + 1048576) {
    const int j = i - base, l = j >> 18, rem = j & 262143;
    a.wqkv[l * 786432 + 524288 + rem] = f2bf(LOADF(9, j));
    return;
  } base += 1048576;
  if (i < base + 4194304) {
    const int j = i - base;
    a.canon[C_W1 + j] = f2bf(LOADF(17, j));
    return;
  } base += 4194304;
  if (i < base + 4194304) {
    const int j = i - base;
    a.canon[C_W2 + j] = f2bf(LOADF(19, j));
    return;
  } base += 4194304;
  if (i < base + 1048576) {
    const int j = i - base;
    a.canon[C_WO + j] = f2bf(LOADF(11, j));
    return;
  } base += 1048576;
  if (i < base + 65536) {
    const int j = i - base;
    a.canon[C_DATA + j] = f2bf(LOADF(0, j));
    return;
  } base += 65536;
  if (i < base + 2048) {
    const int j = i - base, l = j >> 9, r = j & 511;
    a.bqkv[l * 1536 + r] = f2bf(LOADF(6, j) * QSCALE);
    return;
  } base += 2048;
  if (i < base + 2048) {
    const int j = i - base, l = j >> 9, r = j & 511;
    a.bqkv[l * 1536 + 512 + r] = f2bf(LOADF(8, j));
    return;
  } base += 2048;
  if (i < base + 2048) {
    const int j = i - base, l = j >> 9, r = j & 511;
    a.bqkv[l * 1536 + 1024 + r] = f2bf(LOADF(10, j));
    return;
  } base += 2048;
  if (i < base + 2048) { a.canon[C_BO   + i - base] = f2bf(LOADF(12, i - base)); return; } base += 2048;
  if (i < base + 2048) { a.canon[C_LN1G + i - base] = f2bf(LOADF(13, i - base)); return; } base += 2048;
  if (i < base + 2048) { a.canon[C_LN1B + i - base] = f2bf(LOADF(14, i - base)); return; } base += 2048;
  if (i < base + 2048) { a.canon[C_LN2G + i - base] = f2bf(LOADF(15, i - base)); return; } base += 2048;
  if (i < base + 2048) { a.canon[C_LN2B + i - base] = f2bf(LOADF(16, i - base)); return; } base += 2048;
  if (i < base + 8192) { a.canon[C_B1   + i - base] = f2bf(LOADF(18, i - base)); return; } base += 8192;
  if (i < base + 2048) { a.canon[C_B2   + i - base] = f2bf(LOADF(20, i - base)); return; } base += 2048;
  if (i < base + 4)   { a.canon[C_CW + i - base] = f2bf(LOADF(1, i - base)); return; } base += 4;
  if (i < base + 1)   { a.canon[C_CB + i - base] = f2bf(LOADF(2, i - base)); return; } base += 1;
  if (i < base + 512) { a.canon[C_LW + i - base] = f2bf(LOADF(3, i - base)); return; } base += 512;
  if (i < base + 512) { a.canon[C_LB + i - base] = f2bf(LOADF(4, i - base)); return; } base += 512;
  if (i < base + 512) { a.canon[C_WC + i - base] = f2bf(LOADF(21, i - base)); return; } base += 512;
  if (i < base + 1)   { a.canon[C_BC + i - base] = f2bf(LOADF(22, i - base)); return; }
  #undef LOADF
}
#define CONV_TOTAL (3*1048576 + 2*4194304 + 1048576 + 65536 + 3*2048 + 7*2048 + 8192 - 2048 + 4 + 1 + 512 + 512 + 512 + 1)

// ---------------------------------------------------------------------------
// Tiled GEMM, double-buffered LDS (prefetch-after-barrier), 128x128 tile,
// 256 thr = 4 waves (2x2), BK=64. As key: r&7; Bs key: (r>>2)&7 (B-frag rows
// col*4+nt -> coalesced dwordx2 epilogue stores).
// MODE 0: bias  1: bias+relu  4: fused QKV epilogue (Q/K [b,h,p,d], V^T)
// ---------------------------------------------------------------------------
#define BM 128
#define BN 128
#define BK 64

template <int MODE>
__global__ __launch_bounds__(256) void gemm_tile(
    const unsigned short* __restrict__ X, const unsigned short* __restrict__ W,
    const unsigned short* __restrict__ bias, unsigned short* __restrict__ Y,
    int M, int N, int Kd)
{
  __shared__ __align__(16) unsigned short As[2][BM * BK];
  __shared__ __align__(16) unsigned short Bs[2][BN * BK];

  const int tid  = threadIdx.x;
  const int lane = tid & 63;
  const int wave = tid >> 6;
  const int wm = wave & 1, wn = wave >> 1;
  const int col = lane & 15, quad = lane >> 4;

  const int m0 = blockIdx.y * BM;
  const int n0 = blockIdx.x * BN;

  const int srow = tid >> 3;
  const int scb  = tid & 7;

  floatx4 acc[4][4] = {};

  auto stage = [&](int kt, int buf) {
    #pragma unroll
    for (int i = 0; i < 4; i++) {
      const int r  = i * 32 + srow;
      const int cb = scb ^ (r & 7);
      const unsigned short* ga = X + (size_t)(m0 + r) * Kd + kt + cb * 8;
      __builtin_amdgcn_global_load_lds((gptr_t)(const void*)ga,
          (lptr_t)(void*)&As[buf][r * BK + scb * 8], 16, 0, 0);
    }
    #pragma unroll
    for (int i = 0; i < 4; i++) {
      const int r  = i * 32 + srow;
      const int cb = scb ^ ((r >> 2) & 7);
      const unsigned short* gb = W + (size_t)(n0 + r) * Kd + kt + cb * 8;
      __builtin_amdgcn_global_load_lds((gptr_t)(const void*)gb,
          (lptr_t)(void*)&Bs[buf][r * BK + scb * 8], 16, 0, 0);
    }
  };

  const int NT = Kd / BK;
  stage(0, 0);

  for (int c = 0; c < NT; c++) {
    const int buf = c & 1;
    __syncthreads();
    if (c + 1 < NT) stage((c + 1) * BK, buf ^ 1);

    #pragma unroll
    for (int kk = 0; kk < 2; kk++) {
      bf16x8 af[4], bfr[4];
      #pragma unroll
      for (int t = 0; t < 4; t++) {
        const int mr = wm * 64 + t * 16 + col;
        const int ka = (kk * 4 + quad) ^ (mr & 7);
        af[t] = ld8(&As[buf][mr * BK + ka * 8]);
        const int nr = wn * 64 + col * 4 + t;
        const int kb = (kk * 4 + quad) ^ (col & 7);
        bfr[t] = ld8(&Bs[buf][nr * BK + kb * 8]);
      }
      #pragma unroll
      for (int mt = 0; mt < 4; mt++)
        #pragma unroll
        for (int nt = 0; nt < 4; nt++)
          acc[mt][nt] = __builtin_amdgcn_mfma_f32_16x16x32_bf16(af[mt], bfr[nt], acc[mt][nt], 0, 0, 0);
    }
  }

  const int col4 = n0 + wn * 64 + col * 4;
  float bb[4];
  {
    const uint2 bu = *reinterpret_cast<const uint2*>(&bias[col4]);
    bb[0] = bf2f((unsigned short)(bu.x & 0xffffu));
    bb[1] = bf2f((unsigned short)(bu.x >> 16));
    bb[2] = bf2f((unsigned short)(bu.y & 0xffffu));
    bb[3] = bf2f((unsigned short)(bu.y >> 16));
  }

  if (MODE == 4 && (col4 >> 9) == 2) {
    const int cc0 = col4 & 511;
    const int h = cc0 >> 6;
    #pragma unroll
    for (int nt = 0; nt < 4; nt++) {
      const int d = (cc0 + nt) & 63;
      #pragma unroll
      for (int mt = 0; mt < 4; mt++) {
        const int p0 = m0 + wm * 64 + mt * 16 + quad * 4;
        const int b = p0 >> 10, p = p0 & 1023;
        float v0 = acc[mt][nt][0] + bb[nt], v1 = acc[mt][nt][1] + bb[nt];
        float v2 = acc[mt][nt][2] + bb[nt], v3 = acc[mt][nt][3] + bb[nt];
        const size_t idx = 16777216 + (((size_t)(b * NHEAD + h) * DK) + d) * P_SEQ + p;
        *reinterpret_cast<uint2*>(&Y[idx]) = make_uint2(pkbf16(v0, v1), pkbf16(v2, v3));
      }
    }
  } else {
    const int third = col4 >> 9;
    const int cc0 = col4 & 511;
    const int h = cc0 >> 6, d0 = cc0 & 63;
    #pragma unroll
    for (int mt = 0; mt < 4; mt++) {
      #pragma unroll
      for (int r = 0; r < 4; r++) {
        const int rr = m0 + wm * 64 + mt * 16 + quad * 4 + r;
        float v0 = acc[mt][0][r] + bb[0], v1 = acc[mt][1][r] + bb[1];
        float v2 = acc[mt][2][r] + bb[2], v3 = acc[mt][3][r] + bb[3];
        if (MODE == 1) {
          v0 = fmaxf(v0, 0.f); v1 = fmaxf(v1, 0.f);
          v2 = fmaxf(v2, 0.f); v3 = fmaxf(v3, 0.f);
        }
        size_t idx;
        if (MODE == 4) {
          const int b = rr >> 10, p = rr & 1023;
          idx = (size_t)third * 8388608 + (((size_t)(b * NHEAD + h) * P_SEQ) + p) * DK + d0;
        } else {
          idx = (size_t)rr * N + col4;
        }
        *reinterpret_cast<uint2*>(&Y[idx]) = make_uint2(pkbf16(v0, v1), pkbf16(v2, v3));
      }
    }
  }
}

// ---------------------------------------------------------------------------
// Flash attention (round-12 state, known 59.6 us): 40 KB LDS, 4 blocks/CU,
// per-wave Ps reused across q-tiles, conflict-free V path, exp2 fast path,
// coalesced O store through Ps.
// ---------------------------------------------------------------------------
typedef __attribute__((ext_vector_type(8))) unsigned short ushortx8;

__global__ __launch_bounds__(256, 4) void attn_flash8(
    const unsigned short* __restrict__ Q, const unsigned short* __restrict__ K,
    const unsigned short* __restrict__ Vt, unsigned short* __restrict__ O)
{
  __shared__ __align__(16) unsigned short Ks[2][64 * 64];
  __shared__ __align__(16) unsigned short Vs[2][64 * 64];
  __shared__ __align__(16) unsigned short Ps[4][16 * 64];

  const int tid  = threadIdx.x;
  const int lane = tid & 63;
  const int wave = tid >> 6;
  const int col  = lane & 15, quad = lane >> 4;
  const int bh = blockIdx.x & 127;
  const int qb0 = (blockIdx.x >> 7) * 128 + wave * 32;

  const unsigned short* Qh = Q  + (size_t)bh * P_SEQ * DK;
  const unsigned short* Kh = K  + (size_t)bh * P_SEQ * DK;
  const unsigned short* Vh = Vt + (size_t)bh * DK * P_SEQ;

  bf16x8 aq[2][2];
  #pragma unroll
  for (int t = 0; t < 2; t++) {
    aq[t][0] = ld8(Qh + (size_t)(qb0 + t * 16 + col) * DK + quad * 8);
    aq[t][1] = ld8(Qh + (size_t)(qb0 + t * 16 + col) * DK + 32 + quad * 8);
  }

  const ushortx8 one_raw = {0x3F80, 0x3F80, 0x3F80, 0x3F80, 0x3F80, 0x3F80, 0x3F80, 0x3F80};
  const bf16x8 ones = __builtin_bit_cast(bf16x8, one_raw);

  floatx4 o[2][4] = {};
  floatx4 lacc[2] = {};

  const int srow = tid >> 3;
  const int scb  = tid & 7;

  auto stage = [&](int kk, int buf) {
    #pragma unroll
    for (int i = 0; i < 2; i++) {
      const int r  = i * 32 + srow;
      const int cb = scb ^ (r & 7);
      __builtin_amdgcn_global_load_lds(
          (gptr_t)(const void*)(Kh + (size_t)(kk + r) * DK + cb * 8),
          (lptr_t)(void*)&Ks[buf][r * 64 + scb * 8], 16, 0, 0);
      __builtin_amdgcn_global_load_lds(
          (gptr_t)(const void*)(Vh + (size_t)r * P_SEQ + kk + cb * 8),
          (lptr_t)(void*)&Vs[buf][r * 64 + scb * 8], 16, 0, 0);
    }
  };

  stage(0, 0);

  for (int c = 0; c < 16; c++) {
    const int buf = c & 1;
    __syncthreads();
    if (c < 15) stage((c + 1) * 64, buf ^ 1);

    bf16x8 kb0[4], kb1[4];
    #pragma unroll
    for (int nt = 0; nt < 4; nt++) {
      const int kr = nt * 16 + col;
      kb0[nt] = ld8(&Ks[buf][kr * 64 + ((quad       ^ (kr & 7)) << 3)]);
      kb1[nt] = ld8(&Ks[buf][kr * 64 + (((4 + quad) ^ (kr & 7)) << 3)]);
    }

    floatx4 s[2][4] = {};
    #pragma unroll
    for (int t = 0; t < 2; t++)
      #pragma unroll
      for (int nt = 0; nt < 4; nt++) {
        s[t][nt] = __builtin_amdgcn_mfma_f32_16x16x32_bf16(aq[t][0], kb0[nt], s[t][nt], 0, 0, 0);
        s[t][nt] = __builtin_amdgcn_mfma_f32_16x16x32_bf16(aq[t][1], kb1[nt], s[t][nt], 0, 0, 0);
      }

    bf16x8 pa[2][2];
    #pragma unroll
    for (int t = 0; t < 2; t++) {
      #pragma unroll
      for (int r = 0; r < 4; r++) {
        const int row = quad * 4 + r;
        unsigned short* pr = &Ps[wave][row * 64];
        #pragma unroll
        for (int nt = 0; nt < 4; nt++) {
          const float p = fast_exp2(fminf(s[t][nt][r], 126.f));
          union { float f; unsigned int u; } pu; pu.f = p;
          const int key = nt * 16 + col;
          pr[(((key >> 3) ^ (row & 7)) << 3) | (key & 7)] = (unsigned short)(pu.u >> 16);
        }
      }
      __asm__ volatile("s_waitcnt lgkmcnt(0)" ::: "memory");
      pa[t][0] = ld8(&Ps[wave][col * 64 + ((quad       ^ (col & 7)) << 3)]);
      pa[t][1] = ld8(&Ps[wave][col * 64 + (((4 + quad) ^ (col & 7)) << 3)]);
      lacc[t] = __builtin_amdgcn_mfma_f32_16x16x32_bf16(pa[t][0], ones, lacc[t], 0, 0, 0);
      lacc[t] = __builtin_amdgcn_mfma_f32_16x16x32_bf16(pa[t][1], ones, lacc[t], 0, 0, 0);
    }

    #pragma unroll
    for (int dt = 0; dt < 4; dt++) {
      const int dr = dt * 16 + col;
      const bf16x8 v0 = ld8(&Vs[buf][dr * 64 + ((quad       ^ (dr & 7)) << 3)]);
      const bf16x8 v1 = ld8(&Vs[buf][dr * 64 + (((4 + quad) ^ (dr & 7)) << 3)]);
      #pragma unroll
      for (int t = 0; t < 2; t++) {
        o[t][dt] = __builtin_amdgcn_mfma_f32_16x16x32_bf16(pa[t][0], v0, o[t][dt], 0, 0, 0);
        o[t][dt] = __builtin_amdgcn_mfma_f32_16x16x32_bf16(pa[t][1], v1, o[t][dt], 0, 0, 0);
      }
    }
  }

  const int b = bh >> 3, h = bh & 7;
  #pragma unroll
  for (int t = 0; t < 2; t++) {
    #pragma unroll
    for (int r = 0; r < 4; r++) {
      const float inv = 1.f / lacc[t][r];
      unsigned short* pr = &Ps[wave][(quad * 4 + r) * 64];
      #pragma unroll
      for (int dt = 0; dt < 4; dt++)
        pr[dt * 16 + col] = f2bf(o[t][dt][r] * inv);
    }
    __asm__ volatile("s_waitcnt lgkmcnt(0)" ::: "memory");
    #pragma unroll
    for (int r = 0; r < 4; r++) {
      const int p = qb0 + t * 16 + quad * 4 + r;
      const uint2 v = *reinterpret_cast<const uint2*>(&Ps[wave][(quad * 4 + r) * 64 + col * 4]);
      *reinterpret_cast<uint2*>(&O[((size_t)(b * P_SEQ + p)) * E_DIM + h * DK + col * 4]) = v;
    }
  }
}

// ---------------------------------------------------------------------------
// Residual add + LayerNorm, 4 rows/block, in place into X.
// ---------------------------------------------------------------------------
__global__ __launch_bounds__(256) void add_ln4(
    unsigned short* __restrict__ X, const unsigned short* __restrict__ R,
    const unsigned short* __restrict__ g, const unsigned short* __restrict__ bta)
{
  const int row  = blockIdx.x * 4 + (threadIdx.x >> 6);
  const int lane = threadIdx.x & 63;
  const size_t base = (size_t)row * E_DIM + lane * 8;

  uint4 xu = *reinterpret_cast<const uint4*>(X + base);
  uint4 ru = *reinterpret_cast<const uint4*>(R + base);
  unsigned int xs[4] = {xu.x, xu.y, xu.z, xu.w};
  unsigned int rs[4] = {ru.x, ru.y, ru.z, ru.w};

  float v[8];
  float s = 0.f;
  #pragma unroll
  for (int i = 0; i < 4; i++) {
    v[2*i]   = bf2f((unsigned short)(xs[i] & 0xffffu)) + bf2f((unsigned short)(rs[i] & 0xffffu));
    v[2*i+1] = bf2f((unsigned short)(xs[i] >> 16))     + bf2f((unsigned short)(rs[i] >> 16));
    s += v[2*i] + v[2*i+1];
  }
  #pragma unroll
  for (int off = 1; off < 64; off <<= 1) s += __shfl_xor(s, off, 64);
  const float mu = s * (1.f / 512.f);

  float var = 0.f;
  #pragma unroll
  for (int i = 0; i < 8; i++) { float d = v[i] - mu; var += d * d; }
  #pragma unroll
  for (int off = 1; off < 64; off <<= 1) var += __shfl_xor(var, off, 64);
  const float rstd = rsqrtf(var * (1.f / 512.f) + 1e-5f);

  unsigned int ow[4];
  #pragma unroll
  for (int i = 0; i < 4; i++) {
    int e0 = lane * 8 + 2 * i;
    float y0 = (v[2*i]   - mu) * rstd * bf2f(g[e0])     + bf2f(bta[e0]);
    float y1 = (v[2*i+1] - mu) * rstd * bf2f(g[e0 + 1]) + bf2f(bta[e0 + 1]);
    ow[i] = pkbf16(y0, y1);
  }
  *reinterpret_cast<uint4*>(X + base) = make_uint4(ow[0], ow[1], ow[2], ow[3]);
}

// ---------------------------------------------------------------------------
// Embedding: conv(2x2) -> Linear(1->E) -> + positional encoding.
// ---------------------------------------------------------------------------
__global__ __launch_bounds__(64) void embed_kernel(
    const unsigned short* __restrict__ canon, unsigned short* __restrict__ X)
{
  const unsigned short* data   = canon + C_DATA;
  const unsigned short* conv_w = canon + C_CW;
  const unsigned short* conv_b = canon + C_CB;
  const unsigned short* lin_w  = canon + C_LW;
  const unsigned short* lin_b  = canon + C_LB;
  const int bp = blockIdx.x;
  const int b = bp >> 10, p = bp & 1023;
  const int ph = p >> 5, pw = p & 31;
  const unsigned short* dr = data + ((size_t)b * 64 + ph * 2) * 64 + pw * 2;
  const float c = bf2f(dr[0])  * bf2f(conv_w[0]) + bf2f(dr[1])  * bf2f(conv_w[1])
                + bf2f(dr[64]) * bf2f(conv_w[2]) + bf2f(dr[65]) * bf2f(conv_w[3])
                + bf2f(conv_b[0]);
  const int lane = threadIdx.x;
  unsigned int ow[4];
  #pragma unroll
  for (int i = 0; i < 4; i++) {
    const int e0 = lane * 8 + 2 * i;
    const float fr = __expf(-(float)e0 * (9.210340371976184f / 512.f));
    const float ang = (float)p * fr;
    const float v0 = c * bf2f(lin_w[e0])     + bf2f(lin_b[e0])     + sinf(ang);
    const float v1 = c * bf2f(lin_w[e0 + 1]) + bf2f(lin_b[e0 + 1]) + cosf(ang);
    ow[i] = pkbf16(v0, v1);
  }
  *reinterpret_cast<uint4*>(X + (size_t)bp * E_DIM + lane * 8) =
      make_uint4(ow[0], ow[1], ow[2], ow[3]);
}

// ---------------------------------------------------------------------------
// Two-stage mean-pool + classifier.
// ---------------------------------------------------------------------------
__global__ __launch_bounds__(256) void classify_partial(
    const unsigned short* __restrict__ X, const unsigned short* __restrict__ Wc,
    float* __restrict__ partial)
{
  const int b = blockIdx.x, sl = blockIdx.y;
  const int tid = threadIdx.x;
  const unsigned short* xb = X + (size_t)b * P_SEQ * E_DIM + (size_t)sl * 128 * E_DIM;
  float s0 = 0.f, s1 = 0.f;
  for (int p = 0; p < 128; p++) {
    s0 += bf2f(xb[(size_t)p * E_DIM + tid]);
    s1 += bf2f(xb[(size_t)p * E_DIM + tid + 256]);
  }
  float acc = s0 * bf2f(Wc[tid]) + s1 * bf2f(Wc[tid + 256]);
  #pragma unroll
  for (int off = 1; off < 64; off <<= 1) acc += __shfl_xor(acc, off, 64);
  __shared__ float red[4];
  if ((tid & 63) == 0) red[tid >> 6] = acc;
  __syncthreads();
  if (tid == 0) partial[b * 8 + sl] = red[0] + red[1] + red[2] + red[3];
}

__global__ __launch_bounds__(64) void classify_final(
    const float* __restrict__ partial, const unsigned short* __restrict__ bc,
    void* __restrict__ out, const int* __restrict__ flag)
{
  const int b = threadIdx.x;
  if (b >= BATCH) return;
  float s = 0.f;
  #pragma unroll
  for (int i = 0; i < 8; i++) s += partial[b * 8 + i];
  float r = s * (1.f / 1024.f) + bf2f(bc[0]);
  if (*flag) ((float*)out)[b] = r;
  else       ((unsigned short*)out)[b] = f2bf(r);
}

// ---------------------------------------------------------------------------
extern "C" void kernel_launch(void* const* d_in, const int* in_sizes, int n_in,
                              void* d_out, int out_size, void* d_ws, size_t ws_size,
                              hipStream_t stream)
{
  char* ws = (char*)d_ws;
  const size_t MB = (size_t)1 << 20;

  unsigned short* canon = (unsigned short*)ws;                 // ~19 MB
  int* flag = (int*)(ws + 176 * MB);
  float* partial = (float*)(ws + 176 * MB + 256);
  unsigned short* wqkv = (unsigned short*)(ws + 177 * MB);     // [4][1536][512]
  unsigned short* bqkv = (unsigned short*)(ws + 184 * MB);     // [4][1536]

  unsigned short* x    = (unsigned short*)(ws + 32 * MB);
  unsigned short* qb   = (unsigned short*)(ws + 48 * MB);      // q|k|vt packed 48 MB
  unsigned short* attn = (unsigned short*)(ws + 96 * MB);
  unsigned short* hbuf = (unsigned short*)(ws + 112 * MB);
  unsigned short* obuf = (unsigned short*)(ws + 144 * MB);
  unsigned short* fbuf = attn;

  const unsigned short* kb  = qb + 8388608;
  const unsigned short* vtb = qb + 16777216;

  detect_dtype<<<1, 64, 0, stream>>>((const unsigned short*)d_in[0], flag);

  ConvArgs ca;
  for (int i = 0; i < 23; i++) ca.src[i] = d_in[i];
  ca.canon = canon; ca.wqkv = wqkv; ca.bqkv = bqkv; ca.flag = flag;
  convert_pack<<<(CONV_TOTAL + 255) / 256, 256, 0, stream>>>(ca);

  embed_kernel<<<dim3(M_TOK), dim3(64), 0, stream>>>(canon, x);

  for (int l = 0; l < NLAYER; l++) {
    const unsigned short* Wqkv_l = wqkv + (size_t)l * 1536 * 512;
    const unsigned short* bqkv_l = bqkv + l * 1536;
    const unsigned short* Wo_l = canon + C_WO + (size_t)l * E_DIM * E_DIM;
    const unsigned short* W1_l = canon + C_W1 + (size_t)l * FF_DIM * E_DIM;
    const unsigned short* W2_l = canon + C_W2 + (size_t)l * E_DIM * FF_DIM;

    gemm_tile<4><<<dim3(1536 / BN, M_TOK / BM), dim3(256), 0, stream>>>(
        x, Wqkv_l, bqkv_l, qb, M_TOK, 1536, E_DIM);

    attn_flash8<<<dim3((P_SEQ / 128) * BATCH * NHEAD), dim3(256), 0, stream>>>(
        qb, kb, vtb, attn);

    gemm_tile<0><<<dim3(E_DIM / BN, M_TOK / BM), dim3(256), 0, stream>>>(
        attn, Wo_l, canon + C_BO + l * E_DIM, obuf, M_TOK, E_DIM, E_DIM);
    add_ln4<<<dim3(M_TOK / 4), dim3(256), 0, stream>>>(
        x, obuf, canon + C_LN1G + l * E_DIM, canon + C_LN1B + l * E_DIM);

    gemm_tile<1><<<dim3(FF_DIM / BN, M_TOK / BM), dim3(256), 0, stream>>>(
        x, W1_l, canon + C_B1 + l * FF_DIM, hbuf, M_TOK, FF_DIM, E_DIM);
    gemm_tile<0><<<dim3(E_DIM / BN, M_TOK / BM), dim3(256), 0, stream>>>(
        hbuf, W2_l, canon + C_B2 + l * E_DIM, fbuf, M_TOK, E_DIM, FF_DIM);
    add_ln4<<<dim3(M_TOK / 4), dim3(256), 0, stream>>>(
        x, fbuf, canon + C_LN2G + l * E_DIM, canon + C_LN2B + l * E_DIM);
  }

  classify_partial<<<dim3(BATCH, 8), dim3(256), 0, stream>>>(x, canon + C_WC, partial);
  classify_final<<<dim3(1), dim3(64), 0, stream>>>(partial, canon + C_BC, d_out, flag);
}